// Round 3
// baseline (680.668 us; speedup 1.0000x reference)
//
#include <hip/hip_runtime.h>

#define NPTS 4096
#define DIM  256
#define NNB  16

// ---------------- squared norms (f64): sq[j] = sum_d C[d][j]^2 ----------------
__global__ __launch_bounds__(256) void sq_kernel(const float* __restrict__ C,
                                                 double* __restrict__ sq) {
    int j = blockIdx.x * 256 + threadIdx.x;   // 4096 threads exactly
    double s = 0.0;
    for (int d = 0; d < DIM; ++d) {
        double v = (double)C[d * NPTS + j];
        s = fma(v, v, s);
    }
    sq[j] = s;
}

// ------------- fused distance GEMM (f64 accum) + per-row top-16 (partial) -----
// grid: (8 col-tiles of 512, 64 row-tiles of 64); block 256 threads.
// Ranks by squared distance (sqrt is monotone). Exact (f64) values => ordering
// equals true mathematical ordering; stable tie-break by smaller index.
__global__ __launch_bounds__(256) void dist_topk_kernel(
    const float* __restrict__ C, const double* __restrict__ sq,
    double* __restrict__ cand_d, int* __restrict__ cand_i)
{
    __shared__ double At[16][64];        // 8 KB
    __shared__ double Bt[16][64];        // 8 KB
    __shared__ double dtile[64][66];     // 33.8 KB, 8B-aligned rows
    __shared__ double bestd[64][17];     // 8.7 KB
    __shared__ int    besti[64][17];     // 4.4 KB

    const int tid   = threadIdx.x;
    const int i0    = blockIdx.y * 64;
    const int jbase = blockIdx.x * 512;
    const int tx    = tid & 15;
    const int ty    = tid >> 4;

    if (tid < 64) {
        #pragma unroll
        for (int p = 0; p < NNB; ++p) { bestd[tid][p] = __builtin_inf(); besti[tid][p] = -1; }
    }

    double si[4];
    #pragma unroll
    for (int m = 0; m < 4; ++m) si[m] = sq[i0 + ty * 4 + m];

    const int lk = tid >> 4;          // 0..15 : k row within tile
    const int lc = (tid & 15) * 4;    // 0..60 : col (float4 group)

    for (int sub = 0; sub < 8; ++sub) {
        const int j0 = jbase + sub * 64;
        double acc[4][4] = {{0.0}};

        for (int k0 = 0; k0 < DIM; k0 += 16) {
            __syncthreads();
            float4 av = *(const float4*)&C[(k0 + lk) * NPTS + i0 + lc];
            float4 bv = *(const float4*)&C[(k0 + lk) * NPTS + j0 + lc];
            At[lk][lc + 0] = (double)av.x; At[lk][lc + 1] = (double)av.y;
            At[lk][lc + 2] = (double)av.z; At[lk][lc + 3] = (double)av.w;
            Bt[lk][lc + 0] = (double)bv.x; Bt[lk][lc + 1] = (double)bv.y;
            Bt[lk][lc + 2] = (double)bv.z; Bt[lk][lc + 3] = (double)bv.w;
            __syncthreads();
            #pragma unroll
            for (int kk = 0; kk < 16; ++kk) {
                double a[4], b[4];
                #pragma unroll
                for (int m = 0; m < 4; ++m) a[m] = At[kk][ty * 4 + m];
                #pragma unroll
                for (int n = 0; n < 4; ++n) b[n] = Bt[kk][tx * 4 + n];
                #pragma unroll
                for (int m = 0; m < 4; ++m)
                    #pragma unroll
                    for (int n = 0; n < 4; ++n)
                        acc[m][n] = fma(a[m], b[n], acc[m][n]);
            }
        }

        // squared distance, f64: d2 = -2*g + sq_j + sq_i  (no clamp/sqrt needed
        // for ordering; diagonal ~ +-1e-13 is still the row minimum)
        #pragma unroll
        for (int m = 0; m < 4; ++m) {
            #pragma unroll
            for (int n = 0; n < 4; ++n) {
                double dd = fma(-2.0, acc[m][n], sq[j0 + tx * 4 + n]) + si[m];
                dtile[ty * 4 + m][tx * 4 + n] = dd;
            }
        }
        __syncthreads();

        if (tid < 64) {
            double worst = bestd[tid][NNB - 1];
            for (int c = 0; c < 64; ++c) {
                double d = dtile[tid][c];
                if (d < worst) {            // strict <: increasing-j scan keeps stable tie-break
                    int p = NNB - 1;
                    while (p > 0 && d < bestd[tid][p - 1]) {
                        bestd[tid][p] = bestd[tid][p - 1];
                        besti[tid][p] = besti[tid][p - 1];
                        --p;
                    }
                    bestd[tid][p] = d;
                    besti[tid][p] = j0 + c;
                    worst = bestd[tid][NNB - 1];
                }
            }
        }
        __syncthreads();
    }

    if (tid < 64) {
        const int row = i0 + tid;
        #pragma unroll
        for (int p = 0; p < NNB; ++p) {
            cand_d[(row * 8 + blockIdx.x) * NNB + p] = bestd[tid][p];
            cand_i[(row * 8 + blockIdx.x) * NNB + p] = besti[tid][p];
        }
    }
}

// ---------------- merge 128 candidates/row -> final 16 indices ----------
__global__ __launch_bounds__(128) void merge_kernel(const double* __restrict__ cand_d,
                                                    const int* __restrict__ cand_i,
                                                    int* __restrict__ fidx)
{
    __shared__ double ds[128];
    __shared__ int    is_[128];
    const int row = blockIdx.x;
    const int t   = threadIdx.x;
    double d  = cand_d[row * 128 + t];
    int    ix = cand_i[row * 128 + t];
    ds[t] = d; is_[t] = ix;
    __syncthreads();
    int rank = 0;
    for (int o = 0; o < 128; ++o) {
        double od = ds[o]; int oi = is_[o];
        rank += (od < d) || (od == d && oi < ix);   // lexicographic (d2, idx)
    }
    if (rank < NNB) fidx[row * NNB + rank] = ix;
}

// ---------------- gather: dst[r][c] = src[r][fidx[c]], c in [0,65536) ----
__global__ __launch_bounds__(256) void gather_kernel(const float* __restrict__ src,
                                                     const int* __restrict__ fidx,
                                                     float* __restrict__ dst)
{
    const int gid = blockIdx.x * 256 + threadIdx.x;
    const int r   = gid >> 14;            // 16384 float4-groups per row
    const int c4  = (gid & 16383) << 2;
    const int4 id = *(const int4*)&fidx[c4];
    const float* rowp = src + r * NPTS;
    float4 v;
    v.x = rowp[id.x]; v.y = rowp[id.y]; v.z = rowp[id.z]; v.w = rowp[id.w];
    *(float4*)&dst[(size_t)r * 65536 + c4] = v;
}

extern "C" void kernel_launch(void* const* d_in, const int* in_sizes, int n_in,
                              void* d_out, int out_size, void* d_ws, size_t ws_size,
                              hipStream_t stream) {
    const float* xs     = (const float*)d_in[0];
    const float* coords = (const float*)d_in[1];
    float* out = (float*)d_out;

    // Scratch in the TAIL of d_out (inside out1 region; overwritten only by the
    // final gather, which reads nothing from d_out). fidx lives in d_ws.
    //   cand_d: 4096*128 f64 (=2*CAND floats), cand_i: CAND ints, sq: 4096 f64
    const size_t CAND = (size_t)NPTS * 128;            // 524288
    const size_t scratch_floats = 2 * CAND + CAND + 2 * NPTS;
    float* base   = out + ((size_t)out_size - scratch_floats);
    double* cand_d = (double*)base;                    // 8B-aligned (even float offset)
    int*    cand_i = (int*)(base + 2 * CAND);
    double* sq     = (double*)(base + 2 * CAND + CAND);
    int*    fidx   = (int*)d_ws;                       // 4096*16 ints = 256 KB

    sq_kernel<<<NPTS / 256, 256, 0, stream>>>(coords, sq);

    dim3 g2(8, 64);
    dist_topk_kernel<<<g2, 256, 0, stream>>>(coords, sq, cand_d, cand_i);

    merge_kernel<<<NPTS, 128, 0, stream>>>(cand_d, cand_i, fidx);

    // out0: xs gather (1024 x 65536), then out1: coordinates gather (256 x 65536)
    gather_kernel<<<(1024 * 16384) / 256, 256, 0, stream>>>(xs, fidx, out);
    gather_kernel<<<(256 * 16384) / 256, 256, 0, stream>>>(coords, fidx,
                                                           out + (size_t)1024 * 65536);
}

// Round 4
// 401.739 us; speedup vs baseline: 1.6943x; 1.6943x over previous
//
#include <hip/hip_runtime.h>

#define NPTS 4096
#define DIM  256
#define NNB  16
#define NCAND 28   // candidates per row surviving rowtopk (margin over 16)
#define LTOP 6     // per-lane streaming top-L in rowtopk

// ---------------- transpose: Ct[p][d] = C[d][p] ----------------
__global__ __launch_bounds__(256) void transpose_kernel(const float* __restrict__ C,
                                                        float* __restrict__ Ct) {
    __shared__ float T[64][65];
    const int t  = threadIdx.x;
    const int p0 = blockIdx.x * 64;
    const int d0 = blockIdx.y * 64;
    const int r  = t >> 4;          // 0..15
    const int c4 = (t & 15) * 4;    // 0..60
    #pragma unroll
    for (int s = 0; s < 4; ++s) {
        int dl = r + s * 16;
        float4 v = *(const float4*)&C[(size_t)(d0 + dl) * NPTS + p0 + c4];
        T[dl][c4 + 0] = v.x; T[dl][c4 + 1] = v.y;
        T[dl][c4 + 2] = v.z; T[dl][c4 + 3] = v.w;
    }
    __syncthreads();
    #pragma unroll
    for (int s = 0; s < 4; ++s) {
        int pl = r + s * 16;
        float4 v;
        v.x = T[c4 + 0][pl]; v.y = T[c4 + 1][pl];
        v.z = T[c4 + 2][pl]; v.w = T[c4 + 3][pl];
        *(float4*)&Ct[(size_t)(p0 + pl) * DIM + d0 + c4] = v;
    }
}

// ---------------- squared norms (f32) ----------------
__global__ __launch_bounds__(256) void sq_kernel(const float* __restrict__ C,
                                                 float* __restrict__ sq) {
    int j = blockIdx.x * 256 + threadIdx.x;
    float s = 0.0f;
    for (int d = 0; d < DIM; ++d) {
        float v = C[(size_t)d * NPTS + j];
        s = fmaf(v, v, s);
    }
    sq[j] = s;
}

// -------- cheap pass: keys[i][j] = sq_j - 2*<xi,xj>  (f32, 128x128 tiles) ----
__global__ __launch_bounds__(256) void gemm_keys_kernel(const float* __restrict__ C,
                                                        const float* __restrict__ sq,
                                                        float* __restrict__ keys) {
    __shared__ float At[16][128];
    __shared__ float Bt[16][128];
    const int t  = threadIdx.x;
    const int i0 = blockIdx.y * 128;
    const int j0 = blockIdx.x * 128;
    const int tx = t & 15, ty = t >> 4;
    const int lr = t >> 5;          // 0..7
    const int lc = (t & 31) * 4;    // 0..124
    float acc[8][8] = {};
    for (int k0 = 0; k0 < DIM; k0 += 16) {
        __syncthreads();
        #pragma unroll
        for (int s = 0; s < 2; ++s) {
            int kr = lr + s * 8;
            *(float4*)&At[kr][lc] = *(const float4*)&C[(size_t)(k0 + kr) * NPTS + i0 + lc];
            *(float4*)&Bt[kr][lc] = *(const float4*)&C[(size_t)(k0 + kr) * NPTS + j0 + lc];
        }
        __syncthreads();
        #pragma unroll
        for (int kk = 0; kk < 16; ++kk) {
            float a[8], b[8];
            *(float4*)&a[0] = *(const float4*)&At[kk][ty * 8];
            *(float4*)&a[4] = *(const float4*)&At[kk][ty * 8 + 4];
            *(float4*)&b[0] = *(const float4*)&Bt[kk][tx * 8];
            *(float4*)&b[4] = *(const float4*)&Bt[kk][tx * 8 + 4];
            #pragma unroll
            for (int m = 0; m < 8; ++m)
                #pragma unroll
                for (int n = 0; n < 8; ++n)
                    acc[m][n] = fmaf(a[m], b[n], acc[m][n]);
        }
    }
    float sj[8];
    *(float4*)&sj[0] = *(const float4*)&sq[j0 + tx * 8];
    *(float4*)&sj[4] = *(const float4*)&sq[j0 + tx * 8 + 4];
    #pragma unroll
    for (int m = 0; m < 8; ++m) {
        float o[8];
        #pragma unroll
        for (int n = 0; n < 8; ++n) o[n] = fmaf(-2.0f, acc[m][n], sj[n]);
        size_t base = (size_t)(i0 + ty * 8 + m) * NPTS + j0 + tx * 8;
        *(float4*)&keys[base]     = *(float4*)&o[0];
        *(float4*)&keys[base + 4] = *(float4*)&o[4];
    }
}

// -------- per-row approximate top-NCAND: 1 wave/row, per-lane top-6 stream ----
__global__ __launch_bounds__(64) void rowtopk_kernel(const float* __restrict__ keys,
                                                     int* __restrict__ cands) {
    __shared__ float lk[64 * LTOP];
    __shared__ int   li[64 * LTOP];
    const int r    = blockIdx.x;
    const int lane = threadIdx.x;
    const float* row = keys + (size_t)r * NPTS;

    float k0 = __builtin_inff(), k1 = k0, k2 = k0, k3 = k0, k4 = k0, k5 = k0;
    int   j0 = -1, j1 = -1, j2 = -1, j3 = -1, j4 = -1, j5 = -1;

    for (int it = 0; it < NPTS / 64; ++it) {
        int   j = it * 64 + lane;
        float k = row[j];
        if (k < k5) {                       // sorted ascending insert, k5 = worst
            bool b4 = k < k4, b3 = k < k3, b2 = k < k2, b1 = k < k1, b0 = k < k0;
            k5 = b4 ? k4 : k;              j5 = b4 ? j4 : j;
            k4 = b4 ? (b3 ? k3 : k) : k4;  j4 = b4 ? (b3 ? j3 : j) : j4;
            k3 = b3 ? (b2 ? k2 : k) : k3;  j3 = b3 ? (b2 ? j2 : j) : j3;
            k2 = b2 ? (b1 ? k1 : k) : k2;  j2 = b2 ? (b1 ? j1 : j) : j2;
            k1 = b1 ? (b0 ? k0 : k) : k1;  j1 = b1 ? (b0 ? j0 : j) : j1;
            k0 = b0 ? k : k0;              j0 = b0 ? j : j0;
        }
    }
    lk[lane * LTOP + 0] = k0; li[lane * LTOP + 0] = j0;
    lk[lane * LTOP + 1] = k1; li[lane * LTOP + 1] = j1;
    lk[lane * LTOP + 2] = k2; li[lane * LTOP + 2] = j2;
    lk[lane * LTOP + 3] = k3; li[lane * LTOP + 3] = j3;
    lk[lane * LTOP + 4] = k4; li[lane * LTOP + 4] = j4;
    lk[lane * LTOP + 5] = k5; li[lane * LTOP + 5] = j5;
    __syncthreads();
    #pragma unroll
    for (int s = 0; s < LTOP; ++s) {
        float mk = lk[lane * LTOP + s];
        int   mi = li[lane * LTOP + s];
        int rank = 0;
        for (int o = 0; o < 64 * LTOP; ++o) {
            float ok = lk[o];
            int   oi = li[o];
            rank += (ok < mk) || (ok == mk && oi < mi);
        }
        if (rank < NCAND) cands[r * NCAND + rank] = mi;
    }
}

// -------- exact refine: f64 sum of squared diffs on NCAND candidates/row ----
__global__ __launch_bounds__(64) void refine_kernel(const float* __restrict__ Ct,
                                                    const int* __restrict__ cands,
                                                    int* __restrict__ fidx) {
    __shared__ float  xi[DIM];
    __shared__ double dk[NCAND];
    __shared__ int    di[NCAND];
    const int r    = blockIdx.x;
    const int lane = threadIdx.x;
    *(float4*)&xi[lane * 4] = *(const float4*)&Ct[(size_t)r * DIM + lane * 4];
    __syncthreads();
    if (lane < NCAND) {
        int j = cands[r * NCAND + lane];
        const float* xj = &Ct[(size_t)j * DIM];
        double s = 0.0;
        for (int d = 0; d < DIM; d += 4) {
            float4 v = *(const float4*)&xj[d];
            double e0 = (double)xi[d + 0] - (double)v.x; s = fma(e0, e0, s);
            double e1 = (double)xi[d + 1] - (double)v.y; s = fma(e1, e1, s);
            double e2 = (double)xi[d + 2] - (double)v.z; s = fma(e2, e2, s);
            double e3 = (double)xi[d + 3] - (double)v.w; s = fma(e3, e3, s);
        }
        dk[lane] = s; di[lane] = j;
    }
    __syncthreads();
    if (lane < NCAND) {
        double s = dk[lane]; int j = di[lane];
        int rank = 0;
        #pragma unroll
        for (int o = 0; o < NCAND; ++o) {
            double os = dk[o]; int oj = di[o];
            rank += (os < s) || (os == s && oj < j);
        }
        if (rank < NNB) fidx[r * NNB + rank] = j;
    }
}

// ---------------- gather: dst[r][c] = src[r][fidx[c]] ----------------
__global__ __launch_bounds__(256) void gather_kernel(const float* __restrict__ src,
                                                     const int* __restrict__ fidx,
                                                     float* __restrict__ dst)
{
    const int gid = blockIdx.x * 256 + threadIdx.x;
    const int r   = gid >> 14;            // 16384 float4-groups per row
    const int c4  = (gid & 16383) << 2;
    const int4 id = *(const int4*)&fidx[c4];
    const float* rowp = src + (size_t)r * NPTS;
    float4 v;
    v.x = rowp[id.x]; v.y = rowp[id.y]; v.z = rowp[id.z]; v.w = rowp[id.w];
    *(float4*)&dst[(size_t)r * 65536 + c4] = v;
}

extern "C" void kernel_launch(void* const* d_in, const int* in_sizes, int n_in,
                              void* d_out, int out_size, void* d_ws, size_t ws_size,
                              hipStream_t stream) {
    const float* xs     = (const float*)d_in[0];
    const float* coords = (const float*)d_in[1];
    float* out = (float*)d_out;

    // Scratch in the HEAD of d_out (inside out0's 268 MB region; all consumed
    // before the gathers overwrite it). Only fidx (256 KB) lives in d_ws.
    float* keys  = out;                                   // 4096*4096 f32 (67 MB)
    float* Ct    = out + 17825792;                        // 4096*256 f32 (4 MB)
    float* sqv   = Ct + (size_t)NPTS * DIM;               // 4096 f32
    int*   cands = (int*)(sqv + NPTS);                    // 4096*28 i32
    int*   fidx  = (int*)d_ws;                            // 4096*16 i32

    transpose_kernel<<<dim3(64, 4), 256, 0, stream>>>(coords, Ct);
    sq_kernel<<<NPTS / 256, 256, 0, stream>>>(coords, sqv);
    gemm_keys_kernel<<<dim3(32, 32), 256, 0, stream>>>(coords, sqv, keys);
    rowtopk_kernel<<<NPTS, 64, 0, stream>>>(keys, cands);
    refine_kernel<<<NPTS, 64, 0, stream>>>(Ct, cands, fidx);

    gather_kernel<<<(1024 * 16384) / 256, 256, 0, stream>>>(xs, fidx, out);
    gather_kernel<<<(256 * 16384) / 256, 256, 0, stream>>>(coords, fidx,
                                                           out + (size_t)1024 * 65536);
}

// Round 5
// 246.587 us; speedup vs baseline: 2.7604x; 1.6292x over previous
//
#include <hip/hip_runtime.h>

#define NPTS 4096
#define DIM  256
#define NNB  16
#define NCAND 32   // candidates per row surviving rowtopk
#define LTOP 8     // per-lane streaming top-L in rowtopk

using bf16x8 = __attribute__((ext_vector_type(8))) short;
using f32x4  = __attribute__((ext_vector_type(4))) float;

static __device__ __forceinline__ unsigned short f2bf(float f) {
    unsigned u = __float_as_uint(f);
    u += 0x7FFFu + ((u >> 16) & 1u);          // RNE
    return (unsigned short)(u >> 16);
}

// ---- transpose C[d][p] -> Ct[p][d] (f32) and CbT[p][d] (bf16) ----
__global__ __launch_bounds__(256) void transpose_kernel(const float* __restrict__ C,
                                                        float* __restrict__ Ct,
                                                        unsigned short* __restrict__ CbT) {
    __shared__ float T[64][65];
    const int t  = threadIdx.x;
    const int p0 = blockIdx.x * 64;
    const int d0 = blockIdx.y * 64;
    const int r  = t >> 4;          // 0..15
    const int c4 = (t & 15) * 4;    // 0..60
    #pragma unroll
    for (int s = 0; s < 4; ++s) {
        int dl = r + s * 16;
        float4 v = *(const float4*)&C[(size_t)(d0 + dl) * NPTS + p0 + c4];
        T[dl][c4 + 0] = v.x; T[dl][c4 + 1] = v.y;
        T[dl][c4 + 2] = v.z; T[dl][c4 + 3] = v.w;
    }
    __syncthreads();
    #pragma unroll
    for (int s = 0; s < 4; ++s) {
        int pl = r + s * 16;
        float4 v;
        v.x = T[c4 + 0][pl]; v.y = T[c4 + 1][pl];
        v.z = T[c4 + 2][pl]; v.w = T[c4 + 3][pl];
        *(float4*)&Ct[(size_t)(p0 + pl) * DIM + d0 + c4] = v;
        unsigned lo = (unsigned)f2bf(v.x) | ((unsigned)f2bf(v.y) << 16);
        unsigned hi = (unsigned)f2bf(v.z) | ((unsigned)f2bf(v.w) << 16);
        *(uint2*)&CbT[(size_t)(p0 + pl) * DIM + d0 + c4] = make_uint2(lo, hi);
    }
}

// ---- squared norms (f32) ----
__global__ __launch_bounds__(256) void sq_kernel(const float* __restrict__ C,
                                                 float* __restrict__ sq) {
    int j = blockIdx.x * 256 + threadIdx.x;
    float s = 0.0f;
    for (int d = 0; d < DIM; ++d) {
        float v = C[(size_t)d * NPTS + j];
        s = fmaf(v, v, s);
    }
    sq[j] = s;
}

// ---- cheap pass: keys[i][j] = sq_j - 2*<xi,xj> via bf16 MFMA ----
// Block 256 = 4 waves in 2x2; wave computes 64x64 via 4x4 16x16x32 fragments.
// A and B frags use the SAME (lane,elem)->k load formula from k-contiguous
// CbT, so any k-map discrepancy is a shared bijection => Gram value exact.
__global__ __launch_bounds__(256) void gemm_keys_mfma(const unsigned short* __restrict__ CbT,
                                                      const float* __restrict__ sq,
                                                      float* __restrict__ keys) {
    const int t    = threadIdx.x;
    const int wave = t >> 6, lane = t & 63;
    const int i0   = blockIdx.y * 128 + (wave >> 1) * 64;
    const int j0   = blockIdx.x * 128 + (wave & 1) * 64;
    const int lm   = lane & 15;
    const int kg   = (lane >> 4) * 8;      // k-offset, 8 contiguous bf16 = 16B
    f32x4 acc[4][4] = {};
    for (int k0 = 0; k0 < DIM; k0 += 32) {
        bf16x8 a[4], b[4];
        #pragma unroll
        for (int m = 0; m < 4; ++m)
            a[m] = *(const bf16x8*)&CbT[(size_t)(i0 + m * 16 + lm) * DIM + k0 + kg];
        #pragma unroll
        for (int n = 0; n < 4; ++n)
            b[n] = *(const bf16x8*)&CbT[(size_t)(j0 + n * 16 + lm) * DIM + k0 + kg];
        #pragma unroll
        for (int m = 0; m < 4; ++m)
            #pragma unroll
            for (int n = 0; n < 4; ++n)
                acc[m][n] = __builtin_amdgcn_mfma_f32_16x16x32_bf16(a[m], b[n], acc[m][n], 0, 0, 0);
    }
    const int orow = (lane >> 4) * 4;      // C/D: col=lane&15, row=(lane>>4)*4+reg
    #pragma unroll
    for (int n = 0; n < 4; ++n) {
        float sj = sq[j0 + n * 16 + lm];
        #pragma unroll
        for (int m = 0; m < 4; ++m) {
            #pragma unroll
            for (int r = 0; r < 4; ++r)
                keys[(size_t)(i0 + m * 16 + orow + r) * NPTS + j0 + n * 16 + lm] =
                    fmaf(-2.0f, acc[m][n][r], sj);
        }
    }
}

// ---- per-row top-NCAND: per-lane streaming top-8, then 64-way heads merge ----
static __device__ __forceinline__ unsigned long long packki(float k, int j) {
    unsigned u = __float_as_uint(k);
    u ^= ((unsigned)((int)u >> 31)) | 0x80000000u;   // orderable float bits
    return ((unsigned long long)u << 32) | (unsigned)j;
}

__global__ __launch_bounds__(64) void rowtopk_kernel(const float* __restrict__ keys,
                                                     int* __restrict__ cands) {
    const int r    = blockIdx.x;
    const int lane = threadIdx.x;
    const float* row = keys + (size_t)r * NPTS;

    float kk[LTOP]; int jj[LTOP];
    #pragma unroll
    for (int p = 0; p < LTOP; ++p) { kk[p] = __builtin_inff(); jj[p] = 0x7FFFFFFF; }

    for (int it = 0; it < NPTS / 256; ++it) {          // 16 iters, float4/lane
        int jb = it * 256 + lane * 4;
        float4 kv = *(const float4*)&row[jb];
        #pragma unroll
        for (int q = 0; q < 4; ++q) {
            float k = (q == 0) ? kv.x : (q == 1) ? kv.y : (q == 2) ? kv.z : kv.w;
            int   j = jb + q;
            if (k < kk[LTOP - 1]) {
                bool b[LTOP];
                #pragma unroll
                for (int p = 0; p < LTOP; ++p) b[p] = k < kk[p];
                #pragma unroll
                for (int p = LTOP - 1; p >= 1; --p) {
                    kk[p] = b[p - 1] ? kk[p - 1] : (b[p] ? k : kk[p]);
                    jj[p] = b[p - 1] ? jj[p - 1] : (b[p] ? j : jj[p]);
                }
                kk[0] = b[0] ? k : kk[0];
                jj[0] = b[0] ? j : jj[0];
            }
        }
    }

    // 64-way merge: 32 extractions of wave-min over sorted per-lane heads
    for (int e = 0; e < NCAND; ++e) {
        unsigned long long head = packki(kk[0], jj[0]);
        unsigned hi = (unsigned)(head >> 32), lo = (unsigned)head;
        #pragma unroll
        for (int off = 32; off >= 1; off >>= 1) {
            unsigned ohi = __shfl_xor(hi, off), olo = __shfl_xor(lo, off);
            if (ohi < hi || (ohi == hi && olo < lo)) { hi = ohi; lo = olo; }
        }
        if (lane == 0) cands[r * NCAND + e] = (int)lo;
        unsigned long long m = ((unsigned long long)hi << 32) | lo;
        if (head == m) {                                // unique winner pops
            #pragma unroll
            for (int p = 0; p < LTOP - 1; ++p) { kk[p] = kk[p + 1]; jj[p] = jj[p + 1]; }
            kk[LTOP - 1] = __builtin_inff(); jj[LTOP - 1] = 0x7FFFFFFF;
        }
    }
}

// ---- exact refine: f64 sum of squared diffs on NCAND candidates/row ----
__global__ __launch_bounds__(64) void refine_kernel(const float* __restrict__ Ct,
                                                    const int* __restrict__ cands,
                                                    int* __restrict__ fidx) {
    __shared__ float  xi[DIM];
    __shared__ double dk[NCAND];
    __shared__ int    di[NCAND];
    const int r    = blockIdx.x;
    const int lane = threadIdx.x;
    *(float4*)&xi[lane * 4] = *(const float4*)&Ct[(size_t)r * DIM + lane * 4];
    __syncthreads();
    if (lane < NCAND) {
        int j = cands[r * NCAND + lane];
        const float* xj = &Ct[(size_t)j * DIM];
        double s = 0.0;
        for (int d = 0; d < DIM; d += 4) {
            float4 v = *(const float4*)&xj[d];
            double e0 = (double)xi[d + 0] - (double)v.x; s = fma(e0, e0, s);
            double e1 = (double)xi[d + 1] - (double)v.y; s = fma(e1, e1, s);
            double e2 = (double)xi[d + 2] - (double)v.z; s = fma(e2, e2, s);
            double e3 = (double)xi[d + 3] - (double)v.w; s = fma(e3, e3, s);
        }
        dk[lane] = s; di[lane] = j;
    }
    __syncthreads();
    if (lane < NCAND) {
        double s = dk[lane]; int j = di[lane];
        int rank = 0;
        #pragma unroll
        for (int o = 0; o < NCAND; ++o) {
            double os = dk[o]; int oj = di[o];
            rank += (os < s) || (os == s && oj < j);
        }
        if (rank < NNB) fidx[r * NNB + rank] = j;
    }
}

// ---- gather, LDS-staged: one block per output row ----
__global__ __launch_bounds__(256) void gather_row_kernel(const float* __restrict__ src,
                                                         const int* __restrict__ fidx,
                                                         float* __restrict__ dst) {
    __shared__ float row[NPTS];
    const int r = blockIdx.x;
    const int t = threadIdx.x;
    const float* srow = src + (size_t)r * NPTS;
    #pragma unroll
    for (int s = 0; s < NPTS / 1024; ++s)              // 4 iters: 16 KB stage
        *(float4*)&row[(s * 256 + t) * 4] = *(const float4*)&srow[(s * 256 + t) * 4];
    __syncthreads();
    float* drow = dst + (size_t)r * 65536;
    for (int it = 0; it < 65536 / 1024; ++it) {        // 64 iters: 4 KB/iter
        int c4 = (it * 256 + t) * 4;
        int4 id = *(const int4*)&fidx[c4];
        float4 v;
        v.x = row[id.x]; v.y = row[id.y]; v.z = row[id.z]; v.w = row[id.w];
        *(float4*)&drow[c4] = v;
    }
}

extern "C" void kernel_launch(void* const* d_in, const int* in_sizes, int n_in,
                              void* d_out, int out_size, void* d_ws, size_t ws_size,
                              hipStream_t stream) {
    const float* xs     = (const float*)d_in[0];
    const float* coords = (const float*)d_in[1];
    float* out = (float*)d_out;

    // Scratch in the HEAD of d_out (inside out0's 268 MB region; all consumed
    // by refine before the gathers overwrite it). fidx lives in d_ws.
    float*          keys  = out;                                  // 16.78M f32
    float*          Ct    = out + 17825792;                       // 1.05M f32
    unsigned short* CbT   = (unsigned short*)(Ct + (size_t)NPTS * DIM);  // 1.05M bf16
    float*          sqv   = (float*)(CbT + (size_t)NPTS * DIM);   // 4096 f32
    int*            cands = (int*)(sqv + NPTS);                   // 4096*32 i32
    int*            fidx  = (int*)d_ws;                           // 4096*16 i32

    transpose_kernel<<<dim3(64, 4), 256, 0, stream>>>(coords, Ct, CbT);
    sq_kernel<<<NPTS / 256, 256, 0, stream>>>(coords, sqv);
    gemm_keys_mfma<<<dim3(32, 32), 256, 0, stream>>>(CbT, sqv, keys);
    rowtopk_kernel<<<NPTS, 64, 0, stream>>>(keys, cands);
    refine_kernel<<<NPTS, 64, 0, stream>>>(Ct, cands, fidx);

    gather_row_kernel<<<1024, 256, 0, stream>>>(xs, fidx, out);
    gather_row_kernel<<<256, 256, 0, stream>>>(coords, fidx, out + (size_t)1024 * 65536);
}

// Round 6
// 237.569 us; speedup vs baseline: 2.8651x; 1.0380x over previous
//
#include <hip/hip_runtime.h>

#define NPTS 4096
#define DIM  256
#define NNB  16
#define NCAND 32         // candidates per row after merge
#define LTOP  12         // per-scanner streaming top-L
#define CHUNKS 8         // col-chunks (grid.x)
#define JCH   (NPTS / CHUNKS)   // 512 cols per chunk
#define JITERS (JCH / 128)      // 4 j-iters per block
#define NSTR  (CHUNKS * 2)      // 16 streams per row
#define NPART (NSTR * LTOP)     // 192 candidates per row pre-merge

using bf16x8 = __attribute__((ext_vector_type(8))) short;
using f32x4  = __attribute__((ext_vector_type(4))) float;

static __device__ __forceinline__ unsigned short f2bf(float f) {
    unsigned u = __float_as_uint(f);
    u += 0x7FFFu + ((u >> 16) & 1u);          // RNE
    return (unsigned short)(u >> 16);
}

static __device__ __forceinline__ unsigned long long packki(float k, int j) {
    unsigned u = __float_as_uint(k);
    u ^= ((unsigned)((int)u >> 31)) | 0x80000000u;   // orderable float bits
    return ((unsigned long long)u << 32) | (unsigned)j;
}

// ---- transpose C[d][p] -> Ct[p][d] (f32) and CbT[p][d] (bf16) ----
__global__ __launch_bounds__(256) void transpose_kernel(const float* __restrict__ C,
                                                        float* __restrict__ Ct,
                                                        unsigned short* __restrict__ CbT) {
    __shared__ float T[64][65];
    const int t  = threadIdx.x;
    const int p0 = blockIdx.x * 64;
    const int d0 = blockIdx.y * 64;
    const int r  = t >> 4;          // 0..15
    const int c4 = (t & 15) * 4;    // 0..60
    #pragma unroll
    for (int s = 0; s < 4; ++s) {
        int dl = r + s * 16;
        float4 v = *(const float4*)&C[(size_t)(d0 + dl) * NPTS + p0 + c4];
        T[dl][c4 + 0] = v.x; T[dl][c4 + 1] = v.y;
        T[dl][c4 + 2] = v.z; T[dl][c4 + 3] = v.w;
    }
    __syncthreads();
    #pragma unroll
    for (int s = 0; s < 4; ++s) {
        int pl = r + s * 16;
        float4 v;
        v.x = T[c4 + 0][pl]; v.y = T[c4 + 1][pl];
        v.z = T[c4 + 2][pl]; v.w = T[c4 + 3][pl];
        *(float4*)&Ct[(size_t)(p0 + pl) * DIM + d0 + c4] = v;
        unsigned lo = (unsigned)f2bf(v.x) | ((unsigned)f2bf(v.y) << 16);
        unsigned hi = (unsigned)f2bf(v.z) | ((unsigned)f2bf(v.w) << 16);
        *(uint2*)&CbT[(size_t)(p0 + pl) * DIM + d0 + c4] = make_uint2(lo, hi);
    }
}

// ---- squared norms (f32) ----
__global__ __launch_bounds__(256) void sq_kernel(const float* __restrict__ C,
                                                 float* __restrict__ sq) {
    int j = blockIdx.x * 256 + threadIdx.x;
    float s = 0.0f;
    for (int d = 0; d < DIM; ++d) {
        float v = C[(size_t)d * NPTS + j];
        s = fmaf(v, v, s);
    }
    sq[j] = s;
}

// ---- fused: bf16-MFMA keys tile -> LDS -> streaming per-row top-12 ----
// Block: 256 thr (4 waves, 2x2 over 128x128). Grid (CHUNKS, 32).
// Keys never hit global; per-row top-LTOP per scanner stream -> parts.
__global__ __launch_bounds__(256) void gemm_select_kernel(
    const unsigned short* __restrict__ CbT, const float* __restrict__ sq,
    unsigned long long* __restrict__ parts)
{
    __shared__ float tile[128][65];
    const int t    = threadIdx.x;
    const int wave = t >> 6, lane = t & 63;
    const int wr   = wave >> 1, wc = wave & 1;
    const int i0   = blockIdx.y * 128 + wr * 64;
    const int jc0  = blockIdx.x * JCH;
    const int lm   = lane & 15;
    const int kg   = (lane >> 4) * 8;
    const int orow = (lane >> 4) * 4;     // C/D: col=lane&15, row=(lane>>4)*4+reg

    const int srow = t >> 1;              // scanner row 0..127
    const int sS   = t & 1;               // scanner id within row

    float kk[LTOP]; int jj[LTOP];
    #pragma unroll
    for (int p = 0; p < LTOP; ++p) { kk[p] = __builtin_inff(); jj[p] = 0x7FFFFFFF; }

    for (int jit = 0; jit < JITERS; ++jit) {
        const int j0 = jc0 + jit * 128 + wc * 64;   // this wave's 64-col quadrant
        f32x4 acc[4][4] = {};
        for (int k0 = 0; k0 < DIM; k0 += 32) {
            bf16x8 a[4], b[4];
            #pragma unroll
            for (int m = 0; m < 4; ++m)
                a[m] = *(const bf16x8*)&CbT[(size_t)(i0 + m * 16 + lm) * DIM + k0 + kg];
            #pragma unroll
            for (int n = 0; n < 4; ++n)
                b[n] = *(const bf16x8*)&CbT[(size_t)(j0 + n * 16 + lm) * DIM + k0 + kg];
            #pragma unroll
            for (int m = 0; m < 4; ++m)
                #pragma unroll
                for (int n = 0; n < 4; ++n)
                    acc[m][n] = __builtin_amdgcn_mfma_f32_16x16x32_bf16(a[m], b[n], acc[m][n], 0, 0, 0);
        }
        float sj[4];
        #pragma unroll
        for (int n = 0; n < 4; ++n) sj[n] = sq[j0 + n * 16 + lm];

        #pragma unroll
        for (int h = 0; h < 2; ++h) {
            __syncthreads();               // previous scan done before overwrite
            if (wc == h) {                 // this wave's quadrant is in half h
                #pragma unroll
                for (int m = 0; m < 4; ++m)
                    #pragma unroll
                    for (int n = 0; n < 4; ++n)
                        #pragma unroll
                        for (int r = 0; r < 4; ++r)
                            tile[wr * 64 + m * 16 + orow + r][n * 16 + lm] =
                                fmaf(-2.0f, acc[m][n][r], sj[n]);
            }
            __syncthreads();
            const int colbase = sS * 32;
            const int jcol0   = jc0 + jit * 128 + h * 64 + colbase;
            for (int c = 0; c < 32; ++c) {
                float k = tile[srow][colbase + c];
                int   j = jcol0 + c;
                if (k < kk[LTOP - 1]) {    // strict <, ascending j => stable
                    bool b[LTOP];
                    #pragma unroll
                    for (int p = 0; p < LTOP; ++p) b[p] = k < kk[p];
                    #pragma unroll
                    for (int p = LTOP - 1; p >= 1; --p) {
                        kk[p] = b[p - 1] ? kk[p - 1] : (b[p] ? k : kk[p]);
                        jj[p] = b[p - 1] ? jj[p - 1] : (b[p] ? j : jj[p]);
                    }
                    kk[0] = b[0] ? k : kk[0];
                    jj[0] = b[0] ? j : jj[0];
                }
            }
        }
    }

    // stream id = chunk*2 + sS; parts[row][stream][LTOP]
    const int row = blockIdx.y * 128 + srow;
    unsigned long long* dst = &parts[((size_t)row * NSTR + blockIdx.x * 2 + sS) * LTOP];
    #pragma unroll
    for (int p = 0; p < LTOP; ++p) dst[p] = packki(kk[p], jj[p]);
}

// ---- merge 192 candidates/row -> top-32 indices ----
__global__ __launch_bounds__(NPART) void merge_kernel(const unsigned long long* __restrict__ parts,
                                                      int* __restrict__ cands) {
    __shared__ unsigned long long e[NPART];
    const int row = blockIdx.x;
    const int t   = threadIdx.x;
    unsigned long long mine = parts[(size_t)row * NPART + t];
    e[t] = mine;
    __syncthreads();
    int rank = 0;
    for (int o = 0; o < NPART; ++o) rank += e[o] < mine;   // idx tie-break in u64
    if (rank < NCAND) cands[row * NCAND + rank] = (int)(mine & 0xFFFFFFFFu);
}

// ---- exact refine: f64 sum of squared diffs on NCAND candidates/row ----
__global__ __launch_bounds__(64) void refine_kernel(const float* __restrict__ Ct,
                                                    const int* __restrict__ cands,
                                                    int* __restrict__ fidx) {
    __shared__ float  xi[DIM];
    __shared__ double dk[NCAND];
    __shared__ int    di[NCAND];
    const int r    = blockIdx.x;
    const int lane = threadIdx.x;
    *(float4*)&xi[lane * 4] = *(const float4*)&Ct[(size_t)r * DIM + lane * 4];
    __syncthreads();
    if (lane < NCAND) {
        int j = cands[r * NCAND + lane];
        const float* xj = &Ct[(size_t)j * DIM];
        double s = 0.0;
        for (int d = 0; d < DIM; d += 4) {
            float4 v = *(const float4*)&xj[d];
            double e0 = (double)xi[d + 0] - (double)v.x; s = fma(e0, e0, s);
            double e1 = (double)xi[d + 1] - (double)v.y; s = fma(e1, e1, s);
            double e2 = (double)xi[d + 2] - (double)v.z; s = fma(e2, e2, s);
            double e3 = (double)xi[d + 3] - (double)v.w; s = fma(e3, e3, s);
        }
        dk[lane] = s; di[lane] = j;
    }
    __syncthreads();
    if (lane < NCAND) {
        double s = dk[lane]; int j = di[lane];
        int rank = 0;
        #pragma unroll
        for (int o = 0; o < NCAND; ++o) {
            double os = dk[o]; int oj = di[o];
            rank += (os < s) || (os == s && oj < j);
        }
        if (rank < NNB) fidx[r * NNB + rank] = j;
    }
}

// ---- gather (both outputs), LDS-staged: one block per output row ----
__global__ __launch_bounds__(256) void gather_all_kernel(const float* __restrict__ xs,
                                                         const float* __restrict__ coords,
                                                         const int* __restrict__ fidx,
                                                         float* __restrict__ out) {
    __shared__ float row[NPTS];
    const int rb = blockIdx.x;
    const int t  = threadIdx.x;
    const float* srow;
    float* drow;
    if (rb < 1024) { srow = xs + (size_t)rb * NPTS;            drow = out + (size_t)rb * 65536; }
    else           { srow = coords + (size_t)(rb - 1024) * NPTS;
                     drow = out + (size_t)1024 * 65536 + (size_t)(rb - 1024) * 65536; }
    #pragma unroll
    for (int s = 0; s < NPTS / 1024; ++s)              // 4 iters: 16 KB stage
        *(float4*)&row[(s * 256 + t) * 4] = *(const float4*)&srow[(s * 256 + t) * 4];
    __syncthreads();
    for (int it = 0; it < 65536 / 1024; ++it) {        // 64 iters: 4 KB/iter
        int c4 = (it * 256 + t) * 4;
        int4 id = *(const int4*)&fidx[c4];
        float4 v;
        v.x = row[id.x]; v.y = row[id.y]; v.z = row[id.z]; v.w = row[id.w];
        *(float4*)&drow[c4] = v;
    }
}

extern "C" void kernel_launch(void* const* d_in, const int* in_sizes, int n_in,
                              void* d_out, int out_size, void* d_ws, size_t ws_size,
                              hipStream_t stream) {
    const float* xs     = (const float*)d_in[0];
    const float* coords = (const float*)d_in[1];
    float* out = (float*)d_out;

    // Scratch in the HEAD of d_out (inside out0's 268 MB region; all consumed
    // by refine before the gathers overwrite it). fidx lives in d_ws.
    unsigned long long* parts = (unsigned long long*)out;          // 4096*192 u64 = 6.3 MB
    float*          Ct    = out + 1572864;                         // 4096*256 f32
    unsigned short* CbT   = (unsigned short*)(Ct + (size_t)NPTS * DIM);
    float*          sqv   = (float*)(CbT + (size_t)NPTS * DIM);    // 4096 f32
    int*            cands = (int*)(sqv + NPTS);                    // 4096*32 i32
    int*            fidx  = (int*)d_ws;                            // 4096*16 i32

    transpose_kernel<<<dim3(64, 4), 256, 0, stream>>>(coords, Ct, CbT);
    sq_kernel<<<NPTS / 256, 256, 0, stream>>>(coords, sqv);
    gemm_select_kernel<<<dim3(CHUNKS, 32), 256, 0, stream>>>(CbT, sqv, parts);
    merge_kernel<<<NPTS, NPART, 0, stream>>>(parts, cands);
    refine_kernel<<<NPTS, 64, 0, stream>>>(Ct, cands, fidx);
    gather_all_kernel<<<1280, 256, 0, stream>>>(xs, coords, fidx, out);
}

// Round 8
// 189.865 us; speedup vs baseline: 3.5850x; 1.2513x over previous
//
#include <hip/hip_runtime.h>

#define NPTS 4096
#define DIM  256
#define NNB  16
#define NCAND 32         // candidates per row after merge
#define LTOP  12         // per-scanner streaming top-L
#define CHUNKS 8         // col-chunks (grid.x)
#define JCH   (NPTS / CHUNKS)   // 512 cols per chunk
#define JITERS (JCH / 128)      // 4 j-iters per block
#define NSTR  (CHUNKS * 2)      // 16 streams per row
#define NPART (NSTR * LTOP)     // 192 candidates per row pre-merge

using bf16x8 = __attribute__((ext_vector_type(8))) short;
using f32x4  = __attribute__((ext_vector_type(4))) float;

static __device__ __forceinline__ unsigned short f2bf(float f) {
    unsigned u = __float_as_uint(f);
    u += 0x7FFFu + ((u >> 16) & 1u);          // RNE
    return (unsigned short)(u >> 16);
}

static __device__ __forceinline__ unsigned long long packki(float k, int j) {
    unsigned u = __float_as_uint(k);
    u ^= ((unsigned)((int)u >> 31)) | 0x80000000u;   // orderable float bits
    return ((unsigned long long)u << 32) | (unsigned)j;
}

// ---- transpose C[d][p] -> Ct[p][d] (f32) and CbT[p][d] (bf16) ----
__global__ __launch_bounds__(256) void transpose_kernel(const float* __restrict__ C,
                                                        float* __restrict__ Ct,
                                                        unsigned short* __restrict__ CbT) {
    __shared__ float T[64][65];
    const int t  = threadIdx.x;
    const int p0 = blockIdx.x * 64;
    const int d0 = blockIdx.y * 64;
    const int r  = t >> 4;          // 0..15
    const int c4 = (t & 15) * 4;    // 0..60
    #pragma unroll
    for (int s = 0; s < 4; ++s) {
        int dl = r + s * 16;
        float4 v = *(const float4*)&C[(size_t)(d0 + dl) * NPTS + p0 + c4];
        T[dl][c4 + 0] = v.x; T[dl][c4 + 1] = v.y;
        T[dl][c4 + 2] = v.z; T[dl][c4 + 3] = v.w;
    }
    __syncthreads();
    #pragma unroll
    for (int s = 0; s < 4; ++s) {
        int pl = r + s * 16;
        float4 v;
        v.x = T[c4 + 0][pl]; v.y = T[c4 + 1][pl];
        v.z = T[c4 + 2][pl]; v.w = T[c4 + 3][pl];
        *(float4*)&Ct[(size_t)(p0 + pl) * DIM + d0 + c4] = v;
        unsigned lo = (unsigned)f2bf(v.x) | ((unsigned)f2bf(v.y) << 16);
        unsigned hi = (unsigned)f2bf(v.z) | ((unsigned)f2bf(v.w) << 16);
        *(uint2*)&CbT[(size_t)(p0 + pl) * DIM + d0 + c4] = make_uint2(lo, hi);
    }
}

// ---- squared norms (f32) ----
__global__ __launch_bounds__(256) void sq_kernel(const float* __restrict__ C,
                                                 float* __restrict__ sq) {
    int j = blockIdx.x * 256 + threadIdx.x;
    float s = 0.0f;
    for (int d = 0; d < DIM; ++d) {
        float v = C[(size_t)d * NPTS + j];
        s = fmaf(v, v, s);
    }
    sq[j] = s;
}

// ---- fused: bf16-MFMA keys tile -> LDS -> streaming per-row top-12 ----
__global__ __launch_bounds__(256) void gemm_select_kernel(
    const unsigned short* __restrict__ CbT, const float* __restrict__ sq,
    unsigned long long* __restrict__ parts)
{
    __shared__ float tile[128][65];
    const int t    = threadIdx.x;
    const int wave = t >> 6, lane = t & 63;
    const int wr   = wave >> 1, wc = wave & 1;
    const int i0   = blockIdx.y * 128 + wr * 64;
    const int jc0  = blockIdx.x * JCH;
    const int lm   = lane & 15;
    const int kg   = (lane >> 4) * 8;
    const int orow = (lane >> 4) * 4;     // C/D: col=lane&15, row=(lane>>4)*4+reg

    const int srow = t >> 1;              // scanner row 0..127
    const int sS   = t & 1;               // scanner id within row

    float kk[LTOP]; int jj[LTOP];
    #pragma unroll
    for (int p = 0; p < LTOP; ++p) { kk[p] = __builtin_inff(); jj[p] = 0x7FFFFFFF; }

    for (int jit = 0; jit < JITERS; ++jit) {
        const int j0 = jc0 + jit * 128 + wc * 64;   // this wave's 64-col quadrant
        f32x4 acc[4][4] = {};
        for (int k0 = 0; k0 < DIM; k0 += 32) {
            bf16x8 a[4], b[4];
            #pragma unroll
            for (int m = 0; m < 4; ++m)
                a[m] = *(const bf16x8*)&CbT[(size_t)(i0 + m * 16 + lm) * DIM + k0 + kg];
            #pragma unroll
            for (int n = 0; n < 4; ++n)
                b[n] = *(const bf16x8*)&CbT[(size_t)(j0 + n * 16 + lm) * DIM + k0 + kg];
            #pragma unroll
            for (int m = 0; m < 4; ++m)
                #pragma unroll
                for (int n = 0; n < 4; ++n)
                    acc[m][n] = __builtin_amdgcn_mfma_f32_16x16x32_bf16(a[m], b[n], acc[m][n], 0, 0, 0);
        }
        float sj[4];
        #pragma unroll
        for (int n = 0; n < 4; ++n) sj[n] = sq[j0 + n * 16 + lm];

        #pragma unroll
        for (int h = 0; h < 2; ++h) {
            __syncthreads();               // previous scan done before overwrite
            if (wc == h) {                 // this wave's quadrant is in half h
                #pragma unroll
                for (int m = 0; m < 4; ++m)
                    #pragma unroll
                    for (int n = 0; n < 4; ++n)
                        #pragma unroll
                        for (int r = 0; r < 4; ++r)
                            tile[wr * 64 + m * 16 + orow + r][n * 16 + lm] =
                                fmaf(-2.0f, acc[m][n][r], sj[n]);
            }
            __syncthreads();
            const int colbase = sS * 32;
            const int jcol0   = jc0 + jit * 128 + h * 64 + colbase;
            for (int c = 0; c < 32; ++c) {
                float k = tile[srow][colbase + c];
                int   j = jcol0 + c;
                if (k < kk[LTOP - 1]) {    // strict <, ascending j => stable
                    bool b[LTOP];
                    #pragma unroll
                    for (int p = 0; p < LTOP; ++p) b[p] = k < kk[p];
                    #pragma unroll
                    for (int p = LTOP - 1; p >= 1; --p) {
                        kk[p] = b[p - 1] ? kk[p - 1] : (b[p] ? k : kk[p]);
                        jj[p] = b[p - 1] ? jj[p - 1] : (b[p] ? j : jj[p]);
                    }
                    kk[0] = b[0] ? k : kk[0];
                    jj[0] = b[0] ? j : jj[0];
                }
            }
        }
    }

    const int row = blockIdx.y * 128 + srow;
    unsigned long long* dst = &parts[((size_t)row * NSTR + blockIdx.x * 2 + sS) * LTOP];
    #pragma unroll
    for (int p = 0; p < LTOP; ++p) dst[p] = packki(kk[p], jj[p]);
}

// ---- merge 192 candidates/row -> top-32 indices ----
__global__ __launch_bounds__(NPART) void merge_kernel(const unsigned long long* __restrict__ parts,
                                                      int* __restrict__ cands) {
    __shared__ unsigned long long e[NPART];
    const int row = blockIdx.x;
    const int t   = threadIdx.x;
    unsigned long long mine = parts[(size_t)row * NPART + t];
    e[t] = mine;
    __syncthreads();
    int rank = 0;
    for (int o = 0; o < NPART; ++o) rank += e[o] < mine;   // idx tie-break in u64
    if (rank < NCAND) cands[row * NCAND + rank] = (int)(mine & 0xFFFFFFFFu);
}

// ---- exact refine: f64 sum of squared diffs on NCAND candidates/row ----
__global__ __launch_bounds__(64) void refine_kernel(const float* __restrict__ Ct,
                                                    const int* __restrict__ cands,
                                                    int* __restrict__ fidx) {
    __shared__ float  xi[DIM];
    __shared__ double dk[NCAND];
    __shared__ int    di[NCAND];
    const int r    = blockIdx.x;
    const int lane = threadIdx.x;
    *(float4*)&xi[lane * 4] = *(const float4*)&Ct[(size_t)r * DIM + lane * 4];
    __syncthreads();
    if (lane < NCAND) {
        int j = cands[r * NCAND + lane];
        const float* xj = &Ct[(size_t)j * DIM];
        double s = 0.0;
        for (int d = 0; d < DIM; d += 4) {
            float4 v = *(const float4*)&xj[d];
            double e0 = (double)xi[d + 0] - (double)v.x; s = fma(e0, e0, s);
            double e1 = (double)xi[d + 1] - (double)v.y; s = fma(e1, e1, s);
            double e2 = (double)xi[d + 2] - (double)v.z; s = fma(e2, e2, s);
            double e3 = (double)xi[d + 3] - (double)v.w; s = fma(e3, e3, s);
        }
        dk[lane] = s; di[lane] = j;
    }
    __syncthreads();
    if (lane < NCAND) {
        double s = dk[lane]; int j = di[lane];
        int rank = 0;
        #pragma unroll
        for (int o = 0; o < NCAND; ++o) {
            double os = dk[o]; int oj = di[o];
            rank += (os < s) || (os == s && oj < j);
        }
        if (rank < NNB) fidx[r * NNB + rank] = j;
    }
}

// ---- gather v3: grid (2 slices, 1280 rows); fidx reg-prefetch; nt stores ----
__global__ __launch_bounds__(256) void gather_all_kernel(const float* __restrict__ xs,
                                                         const float* __restrict__ coords,
                                                         const int* __restrict__ fidx,
                                                         float* __restrict__ out) {
    __shared__ float row[NPTS];
    const int rb    = blockIdx.y;
    const int slice = blockIdx.x;          // 0..1, 32768 cols each
    const int t     = threadIdx.x;
    const float* srow;
    float* drow;
    if (rb < 1024) { srow = xs + (size_t)rb * NPTS;            drow = out + (size_t)rb * 65536; }
    else           { srow = coords + (size_t)(rb - 1024) * NPTS;
                     drow = out + (size_t)1024 * 65536 + (size_t)(rb - 1024) * 65536; }
    const int cbase = slice * 32768;

    // Issue first fidx group BEFORE the stage barrier (overlaps L2 latency).
    int4 ids[8];
    #pragma unroll
    for (int q = 0; q < 8; ++q)
        ids[q] = *(const int4*)&fidx[cbase + (q * 256 + t) * 4];

    #pragma unroll
    for (int s = 0; s < NPTS / 1024; ++s)              // 4 iters: 16 KB stage
        *(float4*)&row[(s * 256 + t) * 4] = *(const float4*)&srow[(s * 256 + t) * 4];
    __syncthreads();

    for (int g = 0; g < 4; ++g) {                      // 4 groups x 8 iters = 32
        int4 nxt[8];
        if (g < 3) {
            #pragma unroll
            for (int q = 0; q < 8; ++q)
                nxt[q] = *(const int4*)&fidx[cbase + ((g + 1) * 2048 + q * 256 + t) * 4];
        }
        #pragma unroll
        for (int q = 0; q < 8; ++q) {
            int c4 = cbase + (g * 2048 + q * 256 + t) * 4;
            int4 id = ids[q];
            f32x4 v;
            v[0] = row[id.x]; v[1] = row[id.y]; v[2] = row[id.z]; v[3] = row[id.w];
            __builtin_nontemporal_store(v, (f32x4*)&drow[c4]);
        }
        #pragma unroll
        for (int q = 0; q < 8; ++q) ids[q] = nxt[q];
    }
}

extern "C" void kernel_launch(void* const* d_in, const int* in_sizes, int n_in,
                              void* d_out, int out_size, void* d_ws, size_t ws_size,
                              hipStream_t stream) {
    const float* xs     = (const float*)d_in[0];
    const float* coords = (const float*)d_in[1];
    float* out = (float*)d_out;

    unsigned long long* parts = (unsigned long long*)out;          // 4096*192 u64 = 6.3 MB
    float*          Ct    = out + 1572864;                         // 4096*256 f32
    unsigned short* CbT   = (unsigned short*)(Ct + (size_t)NPTS * DIM);
    float*          sqv   = (float*)(CbT + (size_t)NPTS * DIM);    // 4096 f32
    int*            cands = (int*)(sqv + NPTS);                    // 4096*32 i32
    int*            fidx  = (int*)d_ws;                            // 4096*16 i32

    transpose_kernel<<<dim3(64, 4), 256, 0, stream>>>(coords, Ct, CbT);
    sq_kernel<<<NPTS / 256, 256, 0, stream>>>(coords, sqv);
    gemm_select_kernel<<<dim3(CHUNKS, 32), 256, 0, stream>>>(CbT, sqv, parts);
    merge_kernel<<<NPTS, NPART, 0, stream>>>(parts, cands);
    refine_kernel<<<NPTS, 64, 0, stream>>>(Ct, cands, fidx);
    gather_all_kernel<<<dim3(2, 1280), 256, 0, stream>>>(xs, coords, fidx, out);
}